// Round 3
// baseline (198.722 us; speedup 1.0000x reference)
//
#include <hip/hip_runtime.h>
#include <hip/hip_bf16.h>
#include <stdint.h>

typedef __attribute__((ext_vector_type(8))) short short8;
typedef __attribute__((ext_vector_type(4))) float floatx4;

#define FEAT_DIM 1536
#define QD 64
#define NROWS 8192
#define TT 513

__device__ __forceinline__ unsigned short f2bf(float x) {
  union { float f; unsigned u; } t; t.f = x;
  unsigned r = t.u + 0x7fffu + ((t.u >> 16) & 1u);
  return (unsigned short)(r >> 16);
}
__device__ __forceinline__ float bf2f(unsigned short u) {
  union { float f; unsigned u; } t; t.u = ((unsigned)u) << 16;
  return t.f;
}
// monotone float->uint map (order-preserving), low 4 bits freed for an index
__device__ __forceinline__ unsigned packkey(float f, int idx) {
  unsigned x = __float_as_uint(f);
  unsigned m = (unsigned)((int)x >> 31);
  unsigned u = x ^ (m | 0x80000000u);
  return (u & ~15u) | (unsigned)idx;
}
__device__ __forceinline__ float unpackkey(unsigned u) {
  u &= ~15u;
  unsigned x = (u & 0x80000000u) ? (u ^ 0x80000000u) : ~u;
  return __uint_as_float(x);
}

// K0: one-time proj -> bf16 in MFMA B-fragment order.
// prepB[((c*4+sub)*16+n)*4+q][j] = bf16(proj[(c*32+q*8+j)*64 + sub*16 + n])
__global__ __launch_bounds__(256) void k_prep(const float* __restrict__ proj,
                                              unsigned short* __restrict__ prepB) {
  int t = blockIdx.x * 256 + threadIdx.x;   // 0..12287
  int q = t & 3, nn = (t >> 2) & 15, sub = (t >> 6) & 3, c = t >> 8;
  const float* src = proj + (size_t)(c * 32 + q * 8) * QD + sub * 16 + nn;
  union { unsigned short u[8]; short8 v; } P;
#pragma unroll
  for (int j = 0; j < 8; ++j) P.u[j] = f2bf(src[j * QD]);
  *(short8*)(prepB + (size_t)t * 8) = P.v;
}

// K1: fused sf. 2048 blocks x 4 rows x full K (waves = K-quarters, round-0
// summation order). A-fragment rows duplicated x4 (only C rows 0..3 real;
// MFMA was 5% util so the waste is free). Replaces k_sf_part + k_sf_fin:
// one launch fewer, no 16MB sff32 roundtrip, feat traffic ~100MB -> ~61MB
// (g-row of row r == f-row of row r+1 inside the same wave -> L1 hit).
__global__ __launch_bounds__(256, 4) void k_sf4(const float* __restrict__ feat,
                                                const unsigned short* __restrict__ prepB,
                                                unsigned short* __restrict__ sfb,
                                                float* __restrict__ sq) {
  const int tid = threadIdx.x;
  const int wave = tid >> 6, lane = tid & 63;
  const int q = lane >> 4, n = lane & 15;
  const int rbase = blockIdx.x * 4;
  const int row = rbase + (n & 3);
  const int b = row >> 9, ti = row & 511;     // blocks never cross the 512 boundary (512%4==0)
  const float* fb = feat + (size_t)(b * TT + ti) * FEAT_DIM;
  const int kw = wave * 384;
  const short8* pb = (const short8*)prepB + (size_t)(kw >> 5) * 256 + n * 4 + q;

  floatx4 acc0 = {0,0,0,0}, acc1 = {0,0,0,0}, acc2 = {0,0,0,0}, acc3 = {0,0,0,0};

  int koff = kw + q * 8;
  floatx4 f0 = *(const floatx4*)(fb + koff);
  floatx4 f1 = *(const floatx4*)(fb + koff + 4);
  floatx4 g0 = *(const floatx4*)(fb + FEAT_DIM + koff);
  floatx4 g1 = *(const floatx4*)(fb + FEAT_DIM + koff + 4);
  short8 B0 = pb[0], B1 = pb[64], B2 = pb[128], B3 = pb[192];

  for (int ks = 0; ks < 12; ++ks) {
    floatx4 nf0, nf1, ng0, ng1;
    short8 nB0, nB1, nB2, nB3;
    if (ks < 11) {
      int ko = kw + (ks + 1) * 32 + q * 8;
      nf0 = *(const floatx4*)(fb + ko);
      nf1 = *(const floatx4*)(fb + ko + 4);
      ng0 = *(const floatx4*)(fb + FEAT_DIM + ko);
      ng1 = *(const floatx4*)(fb + FEAT_DIM + ko + 4);
      const short8* pn = pb + (ks + 1) * 256;
      nB0 = pn[0]; nB1 = pn[64]; nB2 = pn[128]; nB3 = pn[192];
    }
    __builtin_amdgcn_sched_barrier(0);
    union { unsigned short u[8]; short8 v; } A;
#pragma unroll
    for (int j = 0; j < 4; ++j) A.u[j] = f2bf(0.5f * (f0[j] + g0[j]));
#pragma unroll
    for (int j = 0; j < 4; ++j) A.u[4 + j] = f2bf(0.5f * (f1[j] + g1[j]));
    acc0 = __builtin_amdgcn_mfma_f32_16x16x32_bf16(A.v, B0, acc0, 0, 0, 0);
    acc1 = __builtin_amdgcn_mfma_f32_16x16x32_bf16(A.v, B1, acc1, 0, 0, 0);
    acc2 = __builtin_amdgcn_mfma_f32_16x16x32_bf16(A.v, B2, acc2, 0, 0, 0);
    acc3 = __builtin_amdgcn_mfma_f32_16x16x32_bf16(A.v, B3, acc3, 0, 0, 0);
    if (ks < 11) {
      f0 = nf0; f1 = nf1; g0 = ng0; g1 = ng1;
      B0 = nB0; B1 = nB1; B2 = nB2; B3 = nB3;
    }
  }

  // C row = (lane>>4)*4 + r: real rows (0..3) live in q==0 lanes only.
  __shared__ float part[4][4][64];
  if (q == 0) {
#pragma unroll
    for (int r = 0; r < 4; ++r) {
      part[wave][r][0 * 16 + n] = acc0[r];
      part[wave][r][1 * 16 + n] = acc1[r];
      part[wave][r][2 * 16 + n] = acc2[r];
      part[wave][r][3 * 16 + n] = acc3[r];
    }
  }
  __syncthreads();
  {
    const int r4 = tid >> 6;       // wave index = output row 0..3
    const int col = tid & 63;
    float v = ((part[0][r4][col] + part[1][r4][col]) +
                part[2][r4][col]) + part[3][r4][col];
    unsigned short pu = f2bf(v);
    float bv = bf2f(pu);
    float sqp = bv * bv;
    sfb[(size_t)(rbase + r4) * QD + col] = pu;
#pragma unroll
    for (int off = 1; off < 64; off <<= 1) sqp += __shfl_xor(sqp, off, 64);
    if (col == 0) sq[rbase + r4] = sqp;
  }
}

// K2: round-0 k_knn (measured 60us) + #pragma unroll 2 on the jt loop ONLY.
// Theory: the per-iter A0=nA0 rotation forces a vmcnt-drain wait each iter
// (~300cyc compute vs ~400cyc L2 latency -> ~25% stall = the missing
// VALUBusy). 2-deep double-buffer doubles the latency budget; ILP of the 8
// insertion chains is untouched (R1 showed busy-time is pinned at ~35us and
// ILP is what protects it).
__global__ __launch_bounds__(256, 4) void k_knn(const unsigned short* __restrict__ sfb,
                                                const float* __restrict__ sq,
                                                float* __restrict__ tops) {
  const int tid = threadIdx.x;
  const int wave = tid >> 6, lane = tid & 63;
  const int q = lane >> 4, n = lane & 15;
  const int ib = (blockIdx.x >> 2) * 32;
  const int js = blockIdx.x & 3;
  const short8* sfv = (const short8*)sfb;

  short8 b0 = sfv[(ib + n) * 8 + q];
  short8 b1 = sfv[(ib + n) * 8 + 4 + q];
  short8 b2 = sfv[(ib + 16 + n) * 8 + q];
  short8 b3 = sfv[(ib + 16 + n) * 8 + 4 + q];

  float lst0[16], lst1[16];
#pragma unroll
  for (int k = 0; k < 16; ++k) { lst0[k] = 3.0e38f; lst1[k] = 3.0e38f; }

  const int j0 = js * 2048 + wave * 512;
  short8 A0 = sfv[(j0 + n) * 8 + q];
  short8 A1 = sfv[(j0 + n) * 8 + 4 + q];
  floatx4 s4 = *(const floatx4*)(sq + j0 + q * 4);

#pragma unroll 2
  for (int jt = 0; jt < 512; jt += 16) {
    const int jn = j0 + jt + 16;   // final prefetch overruns into ws scratch: harmless
    short8 nA0 = sfv[(jn + n) * 8 + q];
    short8 nA1 = sfv[(jn + n) * 8 + 4 + q];
    floatx4 ns4 = *(const floatx4*)(sq + jn + q * 4);
    __builtin_amdgcn_sched_barrier(0);

    floatx4 acc0 = {0, 0, 0, 0};
    acc0 = __builtin_amdgcn_mfma_f32_16x16x32_bf16(A0, b0, acc0, 0, 0, 0);
    acc0 = __builtin_amdgcn_mfma_f32_16x16x32_bf16(A1, b1, acc0, 0, 0, 0);
    floatx4 acc1 = {0, 0, 0, 0};
    acc1 = __builtin_amdgcn_mfma_f32_16x16x32_bf16(A0, b2, acc1, 0, 0, 0);
    acc1 = __builtin_amdgcn_mfma_f32_16x16x32_bf16(A1, b3, acc1, 0, 0, 0);

#pragma unroll
    for (int r = 0; r < 4; ++r) {
      float c = fmaf(-2.0f, acc0[r], s4[r]);   // key = sq_j - 2*dot
#pragma unroll
      for (int k = 15; k >= 1; --k)
        lst0[k] = __builtin_amdgcn_fmed3f(lst0[k], lst0[k - 1], c);
      lst0[0] = fminf(lst0[0], c);
    }
#pragma unroll
    for (int r = 0; r < 4; ++r) {
      float c = fmaf(-2.0f, acc1[r], s4[r]);
#pragma unroll
      for (int k = 15; k >= 1; --k)
        lst1[k] = __builtin_amdgcn_fmed3f(lst1[k], lst1[k - 1], c);
      lst1[0] = fminf(lst1[0], c);
    }
    A0 = nA0; A1 = nA1; s4 = ns4;
  }

  __shared__ unsigned lists[16 * 547];
  const int sl = wave * 4 + q;
#pragma unroll
  for (int k = 0; k < 16; ++k) {
    lists[sl * 547 + n * 17 + k] = packkey(lst0[k], sl);
    lists[sl * 547 + (n + 16) * 17 + k] = packkey(lst1[k], sl);
  }
  __syncthreads();

  const int sub = lane & 15;
#pragma unroll 1
  for (int pass = 0; pass < 2; ++pass) {
    const int rr = pass * 16 + wave * 4 + (lane >> 4);   // 0..31
    int p = 0;
    unsigned h = lists[sub * 547 + rr * 17];
    float* trow = tops + ((size_t)(ib + rr) * 4 + js) * 16;
#pragma unroll 1
    for (int it = 0; it < 16; ++it) {
      unsigned u = h;
#pragma unroll
      for (int off = 1; off < 16; off <<= 1) {
        unsigned u2 = __shfl_xor(u, off, 64);
        u = (u2 < u) ? u2 : u;
      }
      if (sub == 0) trow[it] = unpackkey(u);
      if ((u & 15u) == (unsigned)sub) { ++p; h = lists[sub * 547 + rr * 17 + p]; }
    }
  }
}

// K2b: unchanged round-0 merge (tops layout [8192][4][16]).
__global__ __launch_bounds__(256) void k_merge(const float* __restrict__ tops,
                                               const float* __restrict__ sq,
                                               float* __restrict__ intrew,
                                               float* __restrict__ psum) {
  const int tid = threadIdx.x;
  __shared__ float buf[32][68];
  const int ib = blockIdx.x * 32;
  const floatx4* tv = (const floatx4*)(tops + (size_t)ib * 64);
#pragma unroll
  for (int k = 0; k < 2; ++k) {
    int f4 = k * 256 + tid;                  // 0..511 (32 rows x 16 float4)
    floatx4 v = tv[f4];
    int r = f4 >> 4, c = (f4 & 15) * 4;
    *(floatx4*)(&buf[r][c]) = v;
  }
  __syncthreads();
  __shared__ float rsum[1];
  if (tid < 32) {
    const float* bb = buf[tid];
    const int row = ib + tid;
    const float sqr = sq[row];
    int c0 = 1, c1 = 17, c2 = 33, c3 = 49;
    float h0 = bb[0], h1 = bb[16], h2 = bb[32], h3 = bb[48];
    float sum = 0.0f;
#pragma unroll 1
    for (int it = 0; it < 16; ++it) {
      float m = fminf(fminf(h0, h1), fminf(h2, h3));
      sum += sqrtf(fmaxf(sqr + m, 1e-12f));
      if (m == h0)      { h0 = (c0 < 16) ? bb[c0] : 3.0e38f; ++c0; }
      else if (m == h1) { h1 = (c1 < 32) ? bb[c1] : 3.0e38f; ++c1; }
      else if (m == h2) { h2 = (c2 < 48) ? bb[c2] : 3.0e38f; ++c2; }
      else              { h3 = (c3 < 64) ? bb[c3] : 3.0e38f; ++c3; }
    }
    float ir = sum * (1.0f / 16.0f);
    intrew[row] = ir;
    float w = ir;
#pragma unroll
    for (int off = 1; off < 32; off <<= 1) w += __shfl_xor(w, off, 64);
    if (tid == 0) rsum[0] = w;
  }
  __syncthreads();
  if (tid == 0) psum[blockIdx.x] = rsum[0];
}

// K3: StreamNorm + add reward (psum has 256 block sums; shuffle+LDS reduce)
__global__ __launch_bounds__(256) void k_final(const float* __restrict__ reward,
                                               const float* __restrict__ intrew,
                                               const float* __restrict__ psum,
                                               float* __restrict__ out) {
  const int tid = threadIdx.x;
  const int wave = tid >> 6, lane = tid & 63;
  float v = psum[tid];                       // 256 entries
#pragma unroll
  for (int off = 1; off < 64; off <<= 1) v += __shfl_xor(v, off, 64);
  __shared__ float ws4[4];
  if (lane == 0) ws4[wave] = v;
  __syncthreads();
  float total = ws4[0] + ws4[1] + ws4[2] + ws4[3];
  float mean = total * (1.0f / 8192.0f);
  float mag = 0.99f + 0.01f * mean;
  float inv = 1.0f / (mag + 1e-8f);
  int i = blockIdx.x * 256 + tid;            // 0..8191
  int b = i >> 9, ti = i & 511;
  out[i] = reward[b * TT + ti] + intrew[i] * inv;
}

extern "C" void kernel_launch(void* const* d_in, const int* in_sizes, int n_in,
                              void* d_out, int out_size, void* d_ws, size_t ws_size,
                              hipStream_t stream) {
  const float* feat   = (const float*)d_in[0];
  const float* reward = (const float*)d_in[1];
  const float* proj   = (const float*)d_in[2];
  float* out = (float*)d_out;

  char* ws = (char*)d_ws;
  unsigned short* sfb   = (unsigned short*)ws;                 // 1 MB: sf bf16 [8192][64]
  float* sq             = (float*)(ws + 0x100000);             // 32 KB
  float* intrew         = (float*)(ws + 0x110000);             // 32 KB
  float* psum           = (float*)(ws + 0x120000);             // 1 KB (256 floats)
  unsigned short* prepB = (unsigned short*)(ws + 0x130000);    // 192 KB: proj bf16 B-frags
  float* tops           = (float*)(ws + 0x160000);             // 2 MB: [8192][4][16]

  k_prep<<<48, 256, 0, stream>>>(proj, prepB);
  k_sf4<<<2048, 256, 0, stream>>>(feat, prepB, sfb, sq);
  k_knn<<<1024, 256, 0, stream>>>(sfb, sq, tops);
  k_merge<<<256, 256, 0, stream>>>(tops, sq, intrew, psum);
  k_final<<<32, 256, 0, stream>>>(reward, intrew, psum, out);
}

// Round 4
// 150.174 us; speedup vs baseline: 1.3233x; 1.3233x over previous
//
#include <hip/hip_runtime.h>
#include <hip/hip_bf16.h>
#include <stdint.h>

typedef __attribute__((ext_vector_type(8))) short short8;
typedef __attribute__((ext_vector_type(4))) float floatx4;

#define FEAT_DIM 1536
#define QD 64
#define NROWS 8192
#define TT 513

__device__ __forceinline__ unsigned short f2bf(float x) {
  union { float f; unsigned u; } t; t.f = x;
  unsigned r = t.u + 0x7fffu + ((t.u >> 16) & 1u);
  return (unsigned short)(r >> 16);
}
__device__ __forceinline__ float bf2f(unsigned short u) {
  union { float f; unsigned u; } t; t.u = ((unsigned)u) << 16;
  return t.f;
}
// monotone float->uint map (order-preserving), low 4 bits freed for an index
__device__ __forceinline__ unsigned packkey(float f, int idx) {
  unsigned x = __float_as_uint(f);
  unsigned m = (unsigned)((int)x >> 31);
  unsigned u = x ^ (m | 0x80000000u);
  return (u & ~15u) | (unsigned)idx;
}
__device__ __forceinline__ float unpackkey(unsigned u) {
  u &= ~15u;
  unsigned x = (u & 0x80000000u) ? (u ^ 0x80000000u) : ~u;
  return __uint_as_float(x);
}

// K0: one-time proj -> bf16 in MFMA B-fragment order.
// prepB[((c*4+sub)*16+n)*4+q][j] = bf16(proj[(c*32+q*8+j)*64 + sub*16 + n])
__global__ __launch_bounds__(256) void k_prep(const float* __restrict__ proj,
                                              unsigned short* __restrict__ prepB) {
  int t = blockIdx.x * 256 + threadIdx.x;   // 0..12287
  int q = t & 3, nn = (t >> 2) & 15, sub = (t >> 6) & 3, c = t >> 8;
  const float* src = proj + (size_t)(c * 32 + q * 8) * QD + sub * 16 + nn;
  union { unsigned short u[8]; short8 v; } P;
#pragma unroll
  for (int j = 0; j < 8; ++j) P.u[j] = f2bf(src[j * QD]);
  *(short8*)(prepB + (size_t)t * 8) = P.v;
}

// K1a: sf partials, LDS-staged. R0..R3 all carried a ~55-75us latency-bound
// sf stage (R3 finally measured it: 70us, all pipes <9% busy) caused by
// per-lane strided gathers + 1-deep rotate prefetch = one full memory latency
// per K-chunk, serialized. Fix: stage the block's 17x384 f32 feat tile (rows
// are CONTIGUOUS in memory) into LDS with 7 independent coalesced 16B/lane
// loads issued back-to-back (one latency total), B-frags issued in the same
// shadow, then feed MFMA from ds_read_b128. 4-word XOR swizzle (both sides)
// makes every wave LDS access exactly 2 lanes/bank (free, m136).
// Math/accumulation order identical to R2's k_sf_part => bit-identical out.
__global__ __launch_bounds__(256, 4) void k_sfs(const float* __restrict__ feat,
                                                const unsigned short* __restrict__ prepB,
                                                float* __restrict__ sff32) {
  const int tid = threadIdx.x;
  const int wave = tid >> 6, lane = tid & 63;
  const int q = lane >> 4, n = lane & 15;
  const int rowblk = blockIdx.x >> 2, kp = blockIdx.x & 3;
  const int rbase = rowblk * 16;
  const int b = rbase >> 9, ti0 = rbase & 511;   // 16-row blocks never cross b (512%16==0)
  const float* fb0 = feat + (size_t)(b * TT + ti0) * FEAT_DIM;
  const int k0 = kp * 384;

  __shared__ float lds[17 * 384];                // 26112 B, linear (epilogue overlays it)

  // ---- stage: 1632 16B slots over 256 threads = 6 full rounds + 96-thread tail
  floatx4 sv[7];
  int dstw[7];
#pragma unroll
  for (int ri = 0; ri < 7; ++ri) {
    const int slot = ri * 256 + tid;
    const bool ok = (ri < 6) || (tid < 96);
    const int w = slot * 4;
    const int row = w / 384;                     // 0..16
    const int kk = w - row * 384;
    dstw[ri] = row * 384 + (kk ^ ((row & 7) << 2));
    if (ok) sv[ri] = *(const floatx4*)(fb0 + row * FEAT_DIM + k0 + kk);
  }

  // ---- B-fragments for this wave's 3 chunks: issue while staging is in flight
  const short8* pbq = (const short8*)prepB + ((size_t)(k0 + wave * 96) >> 5) * 256 + n * 4 + q;
  short8 Bv0[4], Bv1[4], Bv2[4];
#pragma unroll
  for (int c = 0; c < 4; ++c) {
    Bv0[c] = pbq[c * 64];
    Bv1[c] = pbq[256 + c * 64];
    Bv2[c] = pbq[512 + c * 64];
  }

#pragma unroll
  for (int ri = 0; ri < 7; ++ri)
    if ((ri < 6) || (tid < 96)) *(floatx4*)&lds[dstw[ri]] = sv[ri];
  __syncthreads();

  // ---- compute: wave w owns K-sub [w*96, w*96+96) of this 384 quarter
  floatx4 acc0 = {0,0,0,0}, acc1 = {0,0,0,0}, acc2 = {0,0,0,0}, acc3 = {0,0,0,0};
  const int swf = (n & 7) << 2, swg = ((n + 1) & 7) << 2;
  const int rowf = n * 384, rowg = (n + 1) * 384;
#pragma unroll
  for (int ks = 0; ks < 3; ++ks) {
    const int kb = wave * 96 + ks * 32 + q * 8;
    floatx4 f0 = *(const floatx4*)&lds[rowf + (kb ^ swf)];
    floatx4 f1 = *(const floatx4*)&lds[rowf + ((kb + 4) ^ swf)];
    floatx4 g0 = *(const floatx4*)&lds[rowg + (kb ^ swg)];
    floatx4 g1 = *(const floatx4*)&lds[rowg + ((kb + 4) ^ swg)];
    union { unsigned short u[8]; short8 v; } A;
#pragma unroll
    for (int j = 0; j < 4; ++j) A.u[j] = f2bf(0.5f * (f0[j] + g0[j]));
#pragma unroll
    for (int j = 0; j < 4; ++j) A.u[4 + j] = f2bf(0.5f * (f1[j] + g1[j]));
    const short8* Bc = (ks == 0) ? Bv0 : (ks == 1) ? Bv1 : Bv2;
    acc0 = __builtin_amdgcn_mfma_f32_16x16x32_bf16(A.v, Bc[0], acc0, 0, 0, 0);
    acc1 = __builtin_amdgcn_mfma_f32_16x16x32_bf16(A.v, Bc[1], acc1, 0, 0, 0);
    acc2 = __builtin_amdgcn_mfma_f32_16x16x32_bf16(A.v, Bc[2], acc2, 0, 0, 0);
    acc3 = __builtin_amdgcn_mfma_f32_16x16x32_bf16(A.v, Bc[3], acc3, 0, 0, 0);
  }

  __syncthreads();                               // staged data dead -> overlay as part[]
  float (*part)[16][64] = (float (*)[16][64])lds;
#pragma unroll
  for (int r = 0; r < 4; ++r) {
    part[wave][q * 4 + r][0 * 16 + n] = acc0[r];
    part[wave][q * 4 + r][1 * 16 + n] = acc1[r];
    part[wave][q * 4 + r][2 * 16 + n] = acc2[r];
    part[wave][q * 4 + r][3 * 16 + n] = acc3[r];
  }
  __syncthreads();
  {
    const int r = tid >> 4;
    const int c0 = (tid & 15) * 4;
    floatx4 o;
#pragma unroll
    for (int j = 0; j < 4; ++j)
      o[j] = ((part[0][r][c0 + j] + part[1][r][c0 + j]) +
               part[2][r][c0 + j]) + part[3][r][c0 + j];
    *(floatx4*)(sff32 + ((size_t)kp * NROWS + rbase + r) * QD + c0) = o;
  }
}

// K1b: sum the 4 K-partials (ascending K order, matching the old association),
// round to bf16 (identical f2bf), emit sfb + sq (identical 16-lane reduce).
__global__ __launch_bounds__(256) void k_sf_fin(const float* __restrict__ sff32,
                                                unsigned short* __restrict__ sfb,
                                                float* __restrict__ sq) {
  const int tid = threadIdx.x;
  const int rbase = blockIdx.x * 16;
  const int r = tid >> 4, c0 = (tid & 15) * 4;
  const size_t e = ((size_t)rbase + r) * QD + c0;
  floatx4 v0 = *(const floatx4*)(sff32 + e);
  floatx4 v1 = *(const floatx4*)(sff32 + (size_t)NROWS * QD + e);
  floatx4 v2 = *(const floatx4*)(sff32 + 2 * (size_t)NROWS * QD + e);
  floatx4 v3 = *(const floatx4*)(sff32 + 3 * (size_t)NROWS * QD + e);
  float sqp = 0.0f;
  union { unsigned short u[4]; uint2 d; } P;
#pragma unroll
  for (int j = 0; j < 4; ++j) {
    float v = ((v0[j] + v1[j]) + v2[j]) + v3[j];
    P.u[j] = f2bf(v);
    float bv = bf2f(P.u[j]);
    sqp += bv * bv;
  }
  *(uint2*)(sfb + e) = P.d;
#pragma unroll
  for (int off = 1; off < 16; off <<= 1) sqp += __shfl_xor(sqp, off, 64);
  if ((tid & 15) == 0) sq[rbase + r] = sqp;
}

// K2: round-0 k_knn + unroll 2 (kept from R3; its dur will be directly
// visible in top-5 this round now that sf is fast, resolving the A/B).
__global__ __launch_bounds__(256, 4) void k_knn(const unsigned short* __restrict__ sfb,
                                                const float* __restrict__ sq,
                                                float* __restrict__ tops) {
  const int tid = threadIdx.x;
  const int wave = tid >> 6, lane = tid & 63;
  const int q = lane >> 4, n = lane & 15;
  const int ib = (blockIdx.x >> 2) * 32;
  const int js = blockIdx.x & 3;
  const short8* sfv = (const short8*)sfb;

  short8 b0 = sfv[(ib + n) * 8 + q];
  short8 b1 = sfv[(ib + n) * 8 + 4 + q];
  short8 b2 = sfv[(ib + 16 + n) * 8 + q];
  short8 b3 = sfv[(ib + 16 + n) * 8 + 4 + q];

  float lst0[16], lst1[16];
#pragma unroll
  for (int k = 0; k < 16; ++k) { lst0[k] = 3.0e38f; lst1[k] = 3.0e38f; }

  const int j0 = js * 2048 + wave * 512;
  short8 A0 = sfv[(j0 + n) * 8 + q];
  short8 A1 = sfv[(j0 + n) * 8 + 4 + q];
  floatx4 s4 = *(const floatx4*)(sq + j0 + q * 4);

#pragma unroll 2
  for (int jt = 0; jt < 512; jt += 16) {
    const int jn = j0 + jt + 16;   // final prefetch overruns into ws scratch: harmless
    short8 nA0 = sfv[(jn + n) * 8 + q];
    short8 nA1 = sfv[(jn + n) * 8 + 4 + q];
    floatx4 ns4 = *(const floatx4*)(sq + jn + q * 4);
    __builtin_amdgcn_sched_barrier(0);

    floatx4 acc0 = {0, 0, 0, 0};
    acc0 = __builtin_amdgcn_mfma_f32_16x16x32_bf16(A0, b0, acc0, 0, 0, 0);
    acc0 = __builtin_amdgcn_mfma_f32_16x16x32_bf16(A1, b1, acc0, 0, 0, 0);
    floatx4 acc1 = {0, 0, 0, 0};
    acc1 = __builtin_amdgcn_mfma_f32_16x16x32_bf16(A0, b2, acc1, 0, 0, 0);
    acc1 = __builtin_amdgcn_mfma_f32_16x16x32_bf16(A1, b3, acc1, 0, 0, 0);

#pragma unroll
    for (int r = 0; r < 4; ++r) {
      float c = fmaf(-2.0f, acc0[r], s4[r]);   // key = sq_j - 2*dot
#pragma unroll
      for (int k = 15; k >= 1; --k)
        lst0[k] = __builtin_amdgcn_fmed3f(lst0[k], lst0[k - 1], c);
      lst0[0] = fminf(lst0[0], c);
    }
#pragma unroll
    for (int r = 0; r < 4; ++r) {
      float c = fmaf(-2.0f, acc1[r], s4[r]);
#pragma unroll
      for (int k = 15; k >= 1; --k)
        lst1[k] = __builtin_amdgcn_fmed3f(lst1[k], lst1[k - 1], c);
      lst1[0] = fminf(lst1[0], c);
    }
    A0 = nA0; A1 = nA1; s4 = ns4;
  }

  __shared__ unsigned lists[16 * 547];
  const int sl = wave * 4 + q;
#pragma unroll
  for (int k = 0; k < 16; ++k) {
    lists[sl * 547 + n * 17 + k] = packkey(lst0[k], sl);
    lists[sl * 547 + (n + 16) * 17 + k] = packkey(lst1[k], sl);
  }
  __syncthreads();

  const int sub = lane & 15;
#pragma unroll 1
  for (int pass = 0; pass < 2; ++pass) {
    const int rr = pass * 16 + wave * 4 + (lane >> 4);   // 0..31
    int p = 0;
    unsigned h = lists[sub * 547 + rr * 17];
    float* trow = tops + ((size_t)(ib + rr) * 4 + js) * 16;
#pragma unroll 1
    for (int it = 0; it < 16; ++it) {
      unsigned u = h;
#pragma unroll
      for (int off = 1; off < 16; off <<= 1) {
        unsigned u2 = __shfl_xor(u, off, 64);
        u = (u2 < u) ? u2 : u;
      }
      if (sub == 0) trow[it] = unpackkey(u);
      if ((u & 15u) == (unsigned)sub) { ++p; h = lists[sub * 547 + rr * 17 + p]; }
    }
  }
}

// K2b: unchanged round-0 merge (tops layout [8192][4][16]).
__global__ __launch_bounds__(256) void k_merge(const float* __restrict__ tops,
                                               const float* __restrict__ sq,
                                               float* __restrict__ intrew,
                                               float* __restrict__ psum) {
  const int tid = threadIdx.x;
  __shared__ float buf[32][68];
  const int ib = blockIdx.x * 32;
  const floatx4* tv = (const floatx4*)(tops + (size_t)ib * 64);
#pragma unroll
  for (int k = 0; k < 2; ++k) {
    int f4 = k * 256 + tid;                  // 0..511 (32 rows x 16 float4)
    floatx4 v = tv[f4];
    int r = f4 >> 4, c = (f4 & 15) * 4;
    *(floatx4*)(&buf[r][c]) = v;
  }
  __syncthreads();
  __shared__ float rsum[1];
  if (tid < 32) {
    const float* bb = buf[tid];
    const int row = ib + tid;
    const float sqr = sq[row];
    int c0 = 1, c1 = 17, c2 = 33, c3 = 49;
    float h0 = bb[0], h1 = bb[16], h2 = bb[32], h3 = bb[48];
    float sum = 0.0f;
#pragma unroll 1
    for (int it = 0; it < 16; ++it) {
      float m = fminf(fminf(h0, h1), fminf(h2, h3));
      sum += sqrtf(fmaxf(sqr + m, 1e-12f));
      if (m == h0)      { h0 = (c0 < 16) ? bb[c0] : 3.0e38f; ++c0; }
      else if (m == h1) { h1 = (c1 < 32) ? bb[c1] : 3.0e38f; ++c1; }
      else if (m == h2) { h2 = (c2 < 48) ? bb[c2] : 3.0e38f; ++c2; }
      else              { h3 = (c3 < 64) ? bb[c3] : 3.0e38f; ++c3; }
    }
    float ir = sum * (1.0f / 16.0f);
    intrew[row] = ir;
    float w = ir;
#pragma unroll
    for (int off = 1; off < 32; off <<= 1) w += __shfl_xor(w, off, 64);
    if (tid == 0) rsum[0] = w;
  }
  __syncthreads();
  if (tid == 0) psum[blockIdx.x] = rsum[0];
}

// K3: StreamNorm + add reward (psum has 256 block sums; shuffle+LDS reduce)
__global__ __launch_bounds__(256) void k_final(const float* __restrict__ reward,
                                               const float* __restrict__ intrew,
                                               const float* __restrict__ psum,
                                               float* __restrict__ out) {
  const int tid = threadIdx.x;
  const int wave = tid >> 6, lane = tid & 63;
  float v = psum[tid];                       // 256 entries
#pragma unroll
  for (int off = 1; off < 64; off <<= 1) v += __shfl_xor(v, off, 64);
  __shared__ float ws4[4];
  if (lane == 0) ws4[wave] = v;
  __syncthreads();
  float total = ws4[0] + ws4[1] + ws4[2] + ws4[3];
  float mean = total * (1.0f / 8192.0f);
  float mag = 0.99f + 0.01f * mean;
  float inv = 1.0f / (mag + 1e-8f);
  int i = blockIdx.x * 256 + tid;            // 0..8191
  int b = i >> 9, ti = i & 511;
  out[i] = reward[b * TT + ti] + intrew[i] * inv;
}

extern "C" void kernel_launch(void* const* d_in, const int* in_sizes, int n_in,
                              void* d_out, int out_size, void* d_ws, size_t ws_size,
                              hipStream_t stream) {
  const float* feat   = (const float*)d_in[0];
  const float* reward = (const float*)d_in[1];
  const float* proj   = (const float*)d_in[2];
  float* out = (float*)d_out;

  char* ws = (char*)d_ws;
  unsigned short* sfb   = (unsigned short*)ws;                 // 1 MB: sf bf16 [8192][64]
  float* sq             = (float*)(ws + 0x100000);             // 32 KB
  float* intrew         = (float*)(ws + 0x110000);             // 32 KB
  float* psum           = (float*)(ws + 0x120000);             // 1 KB (256 floats)
  unsigned short* prepB = (unsigned short*)(ws + 0x130000);    // 192 KB: proj bf16 B-frags
  float* tops           = (float*)(ws + 0x160000);             // 2 MB: [8192][4][16]
  float* sff32          = (float*)(ws + 0x360000);             // 8 MB: [4][8192][64] f32 partials

  k_prep<<<48, 256, 0, stream>>>(proj, prepB);
  k_sfs<<<2048, 256, 0, stream>>>(feat, prepB, sff32);
  k_sf_fin<<<512, 256, 0, stream>>>(sff32, sfb, sq);
  k_knn<<<1024, 256, 0, stream>>>(sfb, sq, tops);
  k_merge<<<256, 256, 0, stream>>>(tops, sq, intrew, psum);
  k_final<<<32, 256, 0, stream>>>(reward, intrew, psum, out);
}